// Round 9
// baseline (23.657 us; speedup 1.0000x reference)
//
#include <hip/hip_runtime.h>

// ---------- helpers ----------

__device__ __forceinline__ float rsqz(float d) { return rsqrtf(fmaxf(d, 1e-24f)); }

__device__ __forceinline__ void angNorm(float x, float y, float& c, float& s) {
    float inv = rsqz(x*x + y*y);
    c = x * inv; s = y * inv;
}

// row-vector times 4x4 matrix (matrix loaded row-major via 4x float4)
__device__ __forceinline__ float4 rowMat(const float4 f, const float* __restrict__ B) {
    const float4* q = reinterpret_cast<const float4*>(B);
    float4 b0 = q[0], b1 = q[1], b2 = q[2], b3 = q[3];
    float4 o;
    o.x = f.x*b0.x + f.y*b1.x + f.z*b2.x + f.w*b3.x;
    o.y = f.x*b0.y + f.y*b1.y + f.z*b2.y + f.w*b3.y;
    o.z = f.x*b0.z + f.y*b1.z + f.z*b2.z + f.w*b3.z;
    o.w = f.x*b0.w + f.y*b1.w + f.z*b2.w + f.w*b3.w;
    return o;
}

__device__ __forceinline__ void rotXrow(float4& v, float c, float s) {
    float v1 = v.y, v2 = v.z;
    v.y = c*v1 + s*v2;
    v.z = c*v2 - s*v1;
}

__device__ __forceinline__ void rotZrow(float4& v, float c, float s) {
    float v0 = v.x, v1 = v.y;
    v.x = c*v0 + s*v1;
    v.y = c*v1 - s*v0;
}

// post-multiply row by homogeneous rotation (3x3 G): out.xyz = f.xyz * G; out.w = f.w
__device__ __forceinline__ float4 applyG(const float4 f, const float G[3][3]) {
    float4 o;
    o.x = f.x*G[0][0] + f.y*G[1][0] + f.z*G[2][0];
    o.y = f.x*G[0][1] + f.y*G[1][1] + f.z*G[2][1];
    o.z = f.x*G[0][2] + f.y*G[1][2] + f.z*G[2][2];
    o.w = f.w;
    return o;
}

__device__ __forceinline__ void rotAxis3(float G[3][3], float c, float s,
                                         float u0, float u1, float u2) {
    float omc = 1.0f - c;
    G[0][0] = c + u0*u0*omc;    G[0][1] = u0*u1*omc - u2*s; G[0][2] = u0*u2*omc + u1*s;
    G[1][0] = u0*u1*omc + u2*s; G[1][1] = c + u1*u1*omc;    G[1][2] = u1*u2*omc - u0*s;
    G[2][0] = u0*u2*omc - u1*s; G[2][1] = u1*u2*omc + u0*s; G[2][2] = c + u2*u2*omc;
}

// ---------------------------- kernel A: frames ----------------------------
// 4 lanes per residue, lane i carries row i of every frame through the
// recurrence F_next = F_prev @ M (row-decomposable). Identical code on all
// lanes (row 3 starts (0,0,0,1)); prefix math redundant across the 4 lanes.
// No LDS, no barriers. Frames written straight to global from registers.

__global__ __launch_bounds__(256, 2) void frames_kernel(
    const int*   __restrict__ seq,     // (BL)
    const float* __restrict__ xyz,     // (BL,3,3)
    const float* __restrict__ alphas,  // (BL,10,2)
    const float* __restrict__ RTs,     // (NAA,7,4,4)
    const float* __restrict__ xibf,    // (NAA,36,4)
    float*       __restrict__ out_fr,  // (BL,9,4,4)
    int BL)
{
    const int tid  = blockIdx.x * 256 + threadIdx.x;
    const int i    = tid & 3;            // row index 0..3
    const int t    = tid >> 2;           // residue
    if (t >= BL) return;

    int s = seq[t];
    const float* rb = RTs + (size_t)s * 112;
    const float* al = alphas + (size_t)t * 20;
    float* fg = out_fr + (size_t)t * 144;

    // ---- Gram-Schmidt (redundant across the 4 lanes) ----
    const float* p = xyz + (size_t)t * 9;
    float N0=p[0], N1=p[1], N2=p[2];
    float A0=p[3], A1=p[4], A2=p[5];
    float C0=p[6], C1=p[7], C2=p[8];
    float v10=C0-A0, v11=C1-A1, v12=C2-A2;
    float v20=N0-A0, v21=N1-A1, v22=N2-A2;
    float i1 = rsqz(v10*v10 + v11*v11 + v12*v12);
    float e10=v10*i1, e11=v11*i1, e12=v12*i1;
    float d  = e10*v20 + e11*v21 + e12*v22;
    float u20=v20-e10*d, u21=v21-e11*d, u22=v22-e12*d;
    float i2 = rsqz(u20*u20 + u21*u21 + u22*u22);
    float e20=u20*i2, e21=u21*i2, e22=u22*i2;
    float e30=e11*e22 - e12*e21;
    float e31=e12*e20 - e10*e22;
    float e32=e10*e21 - e11*e20;

    bool s0 = (i==0), s1 = (i==1), s2 = (i==2);
    float4 f0r;
    f0r.x = s0?e10 : s1?e11 : s2?e12 : 0.f;
    f0r.y = s0?e20 : s1?e21 : s2?e22 : 0.f;
    f0r.z = s0?e30 : s1?e31 : s2?e32 : 0.f;
    f0r.w = s0?A0  : s1?A1  : s2?A2  : 1.f;
    *reinterpret_cast<float4*>(fg + i*4) = f0r;

    // ---- angles ----
    const float4* a4p = reinterpret_cast<const float4*>(al);
    float4 q0 = a4p[0], q1 = a4p[1], q2 = a4p[2], q3 = a4p[3], q4 = a4p[4];
    float ca0,sa0, ca1,sa1, ca2,sa2, ca3,sa3, ca4,sa4;
    float ca5,sa5, ca6,sa6, ca7,sa7, ca8,sa8, ca9,sa9;
    angNorm(q0.x,q0.y, ca0,sa0);  angNorm(q0.z,q0.w, ca1,sa1);
    angNorm(q1.x,q1.y, ca2,sa2);  angNorm(q1.z,q1.w, ca3,sa3);
    angNorm(q2.x,q2.y, ca4,sa4);  angNorm(q2.z,q2.w, ca5,sa5);
    angNorm(q3.x,q3.y, ca6,sa6);  angNorm(q3.z,q3.w, ca7,sa7);
    angNorm(q4.x,q4.y, ca8,sa8);  angNorm(q4.z,q4.w, ca9,sa9);

    // ---- F1..F3 ----
    float4 rw;
    rw = rowMat(f0r, rb +  0); rotXrow(rw, ca0, sa0);
    *reinterpret_cast<float4*>(fg + 16 + i*4) = rw;
    rw = rowMat(f0r, rb + 16); rotXrow(rw, ca1, sa1);
    *reinterpret_cast<float4*>(fg + 32 + i*4) = rw;
    rw = rowMat(f0r, rb + 32); rotXrow(rw, ca2, sa2);
    *reinterpret_cast<float4*>(fg + 48 + i*4) = rw;

    // ---- CB axes (redundant) ----
    const float* bxp = xibf + (size_t)s * 144;
    float4 b0 = reinterpret_cast<const float4*>(bxp)[0];
    float4 b1 = reinterpret_cast<const float4*>(bxp)[1];
    float4 b2 = reinterpret_cast<const float4*>(bxp)[2];
    float4 b4 = reinterpret_cast<const float4*>(bxp)[4];

    float NCr0 = 0.5f*(b2.x + b0.x), NCr1 = 0.5f*(b2.y + b0.y), NCr2 = 0.5f*(b2.z + b0.z);
    float ba0 = b4.x - b1.x, ba1 = b4.y - b1.y, ba2 = b4.z - b1.z;
    float w0 = NCr0 - b1.x, w1 = NCr1 - b1.y, w2 = NCr2 - b1.z;
    float x10 = ba1*w2 - ba2*w1, x11 = ba2*w0 - ba0*w2, x12 = ba0*w1 - ba1*w0;
    float in1 = rsqz(x10*x10 + x11*x11 + x12*x12);
    x10 *= in1; x11 *= in1; x12 *= in1;
    float NCp0 = b2.x - b0.x, NCp1 = b2.y - b0.y, NCp2 = b2.z - b0.z;
    float dp = NCp0*NCr0 + NCp1*NCr1 + NCp2*NCr2;
    float dr = NCr0*NCr0 + NCr1*NCr1 + NCr2*NCr2;
    float sf = dp / dr;
    float g0 = NCp0 - sf*NCr0, g1 = NCp1 - sf*NCr1, g2 = NCp2 - sf*NCr2;
    float x20 = ba1*g2 - ba2*g1, x21 = ba2*g0 - ba0*g2, x22 = ba0*g1 - ba1*g0;
    float in2 = rsqz(x20*x20 + x21*x21 + x22*x22);
    x20 *= in2; x21 *= in2; x22 *= in2;

    float G1[3][3], G2[3][3];
    rotAxis3(G1, ca7, sa7, x10, x11, x12);
    rotAxis3(G2, ca8, sa8, x20, x21, x22);

    // ---- F8 ----
    float4 f8r = applyG(applyG(f0r, G1), G2);
    *reinterpret_cast<float4*>(fg + 128 + i*4) = f8r;

    // ---- F4..F7 suffix chain ----
    rw = rowMat(f8r, rb + 48); rotXrow(rw, ca3, sa3); rotZrow(rw, ca9, sa9);
    *reinterpret_cast<float4*>(fg + 64 + i*4) = rw;
    rw = rowMat(rw, rb + 64); rotXrow(rw, ca4, sa4);
    *reinterpret_cast<float4*>(fg + 80 + i*4) = rw;
    rw = rowMat(rw, rb + 80); rotXrow(rw, ca5, sa5);
    *reinterpret_cast<float4*>(fg + 96 + i*4) = rw;
    rw = rowMat(rw, rb + 96); rotXrow(rw, ca6, sa6);
    *reinterpret_cast<float4*>(fg + 112 + i*4) = rw;
}

// ---------------------------- kernel B: atoms ----------------------------
// One thread per atom: massive parallelism (18K waves) hides all gather
// latency. Frames read back through L2/L3 (just written by kernel A).

__global__ __launch_bounds__(256) void atoms_kernel(
    const int*   __restrict__ seq,      // (BL)
    const int*   __restrict__ bidx,     // (NAA,36)
    const float* __restrict__ xibf,     // (NAA,36,4)
    const float* __restrict__ frames,   // (BL,9,4,4)
    float*       __restrict__ out_xyz,  // (BL,36,3)
    int BL)
{
    int g = blockIdx.x * 256 + threadIdx.x;
    if (g >= BL * 36) return;
    int t = g / 36;
    int a = g - t * 36;
    int s = seq[t];
    int idx = bidx[s * 36 + a];

    const float4* fr = reinterpret_cast<const float4*>(frames + ((size_t)t * 9 + idx) * 16);
    float4 r0 = fr[0], r1 = fr[1], r2 = fr[2];
    float4 v  = *reinterpret_cast<const float4*>(xibf + ((size_t)s * 36 + a) * 4);

    float x = r0.x*v.x + r0.y*v.y + r0.z*v.z + r0.w*v.w;
    float y = r1.x*v.x + r1.y*v.y + r1.z*v.z + r1.w*v.w;
    float z = r2.x*v.x + r2.y*v.y + r2.z*v.z + r2.w*v.w;

    size_t o = (size_t)g * 3;
    out_xyz[o+0] = x;
    out_xyz[o+1] = y;
    out_xyz[o+2] = z;
}

// ---------------------------- launch ----------------------------

extern "C" void kernel_launch(void* const* d_in, const int* in_sizes, int n_in,
                              void* d_out, int out_size, void* d_ws, size_t ws_size,
                              hipStream_t stream) {
    const int*   seq    = (const int*)  d_in[0];
    const float* xyz    = (const float*)d_in[1];
    const float* alphas = (const float*)d_in[2];
    const int*   bidx   = (const int*)  d_in[3];
    const float* RTs    = (const float*)d_in[4];
    const float* xibf   = (const float*)d_in[5];
    float*       out    = (float*)d_out;

    int BL = in_sizes[0];                       // B * L
    float* out_xyz = out + (size_t)BL * 144;

    int blocksA = (BL * 4 + 255) / 256;
    frames_kernel<<<blocksA, 256, 0, stream>>>(seq, xyz, alphas, RTs, xibf, out, BL);

    int blocksB = (BL * 36 + 255) / 256;
    atoms_kernel<<<blocksB, 256, 0, stream>>>(seq, bidx, xibf, out, out_xyz, BL);
}

// Round 10
// 17.446 us; speedup vs baseline: 1.3560x; 1.3560x over previous
//
#include <hip/hip_runtime.h>

#define RPB 64              // residues per block
#define FRS 20              // LDS floats per frame (16 + 4 pad), 16B-aligned rows
#define RSS (9*FRS)         // 180 floats per residue (720B)

// ---------- helpers ----------

__device__ __forceinline__ float rsqz(float d) { return rsqrtf(fmaxf(d, 1e-24f)); }

__device__ __forceinline__ void angNorm(float x, float y, float& c, float& s) {
    float inv = rsqz(x*x + y*y);
    c = x * inv; s = y * inv;
}

// row-vector times 4x4 matrix (matrix row-major, 4x float4)
__device__ __forceinline__ float4 rowMat(const float4 f, const float* __restrict__ B) {
    const float4* q = reinterpret_cast<const float4*>(B);
    float4 b0 = q[0], b1 = q[1], b2 = q[2], b3 = q[3];
    float4 o;
    o.x = f.x*b0.x + f.y*b1.x + f.z*b2.x + f.w*b3.x;
    o.y = f.x*b0.y + f.y*b1.y + f.z*b2.y + f.w*b3.y;
    o.z = f.x*b0.z + f.y*b1.z + f.z*b2.z + f.w*b3.z;
    o.w = f.x*b0.w + f.y*b1.w + f.z*b2.w + f.w*b3.w;
    return o;
}

__device__ __forceinline__ void rotXrow(float4& v, float c, float s) {
    float v1 = v.y, v2 = v.z;
    v.y = c*v1 + s*v2;
    v.z = c*v2 - s*v1;
}

__device__ __forceinline__ void rotZrow(float4& v, float c, float s) {
    float v0 = v.x, v1 = v.y;
    v.x = c*v0 + s*v1;
    v.y = c*v1 - s*v0;
}

__device__ __forceinline__ float4 applyG(const float4 f, const float G[3][3]) {
    float4 o;
    o.x = f.x*G[0][0] + f.y*G[1][0] + f.z*G[2][0];
    o.y = f.x*G[0][1] + f.y*G[1][1] + f.z*G[2][1];
    o.z = f.x*G[0][2] + f.y*G[1][2] + f.z*G[2][2];
    o.w = f.w;
    return o;
}

__device__ __forceinline__ void rotAxis3(float G[3][3], float c, float s,
                                         float u0, float u1, float u2) {
    float omc = 1.0f - c;
    G[0][0] = c + u0*u0*omc;    G[0][1] = u0*u1*omc - u2*s; G[0][2] = u0*u2*omc + u1*s;
    G[1][0] = u0*u1*omc + u2*s; G[1][1] = c + u1*u1*omc;    G[1][2] = u1*u2*omc - u0*s;
    G[2][0] = u0*u2*omc - u1*s; G[2][1] = u1*u2*omc + u0*s; G[2][2] = c + u2*u2*omc;
}

// ---------------------------- fused kernel ----------------------------
// 512 threads = 8 waves, 64 residues/block.
// Waves 0-3: frame phase — 4 lanes per residue carry rows of the
//   recurrence F_next = F_prev @ M (row-decomposable); identical code on
//   all lanes; frames -> LDS (for atom gather) + global (from registers).
// Waves 4-7: prefetch their atom gathers (seq/bidx/xibf — independent of
//   frames) into registers, overlapping latency under the frame phase.
// One barrier, then all 8 waves share the 2304 atom transforms.

__global__ __launch_bounds__(512, 4) void fused_kernel(
    const int*   __restrict__ seq,     // (BL)
    const float* __restrict__ xyz,     // (BL,3,3)
    const float* __restrict__ alphas,  // (BL,10,2)
    const int*   __restrict__ bidx,    // (NAA,36)
    const float* __restrict__ RTs,     // (NAA,7,4,4)
    const float* __restrict__ xibf,    // (NAA,36,4)
    float*       __restrict__ out_fr,  // (BL,9,4,4)
    float*       __restrict__ out_xyz, // (BL,36,3)
    int BL)
{
    __shared__ __align__(16) float lds_fr[RPB * RSS];   // 46.1 KB
    __shared__ int lds_seq[RPB];

    const int tid  = threadIdx.x;
    const int lane = tid & 63;
    const int wv   = tid >> 6;
    const int base = blockIdx.x * RPB;

    int    pf_idx[5];
    float4 pf_v[5];

    if (wv < 4) {
        // ---------------- frame phase ----------------
        const int i   = lane & 3;                 // row 0..3
        const int res = wv*16 + (lane >> 2);      // residue 0..63
        const int t   = base + res;
        if (t < BL) {
            int s = seq[t];
            if (i == 0) lds_seq[res] = s;
            const float* rb = RTs + (size_t)s * 112;
            const float* al = alphas + (size_t)t * 20;
            float* fl = lds_fr + res * RSS;
            float* fg = out_fr + (size_t)t * 144;

            // Gram-Schmidt (redundant across the 4 lanes)
            const float* p = xyz + (size_t)t * 9;
            float N0=p[0], N1=p[1], N2=p[2];
            float A0=p[3], A1=p[4], A2=p[5];
            float C0=p[6], C1=p[7], C2=p[8];
            float v10=C0-A0, v11=C1-A1, v12=C2-A2;
            float v20=N0-A0, v21=N1-A1, v22=N2-A2;
            float i1 = rsqz(v10*v10 + v11*v11 + v12*v12);
            float e10=v10*i1, e11=v11*i1, e12=v12*i1;
            float d  = e10*v20 + e11*v21 + e12*v22;
            float u20=v20-e10*d, u21=v21-e11*d, u22=v22-e12*d;
            float i2 = rsqz(u20*u20 + u21*u21 + u22*u22);
            float e20=u20*i2, e21=u21*i2, e22=u22*i2;
            float e30=e11*e22 - e12*e21;
            float e31=e12*e20 - e10*e22;
            float e32=e10*e21 - e11*e20;

            bool c0 = (i==0), c1 = (i==1), c2 = (i==2);
            float4 f0r;
            f0r.x = c0?e10 : c1?e11 : c2?e12 : 0.f;
            f0r.y = c0?e20 : c1?e21 : c2?e22 : 0.f;
            f0r.z = c0?e30 : c1?e31 : c2?e32 : 0.f;
            f0r.w = c0?A0  : c1?A1  : c2?A2  : 1.f;
            *reinterpret_cast<float4*>(fl + i*4) = f0r;
            *reinterpret_cast<float4*>(fg + i*4) = f0r;

            // angles
            const float4* a4p = reinterpret_cast<const float4*>(al);
            float4 q0 = a4p[0], q1 = a4p[1], q2 = a4p[2], q3 = a4p[3], q4 = a4p[4];
            float ca0,sa0, ca1,sa1, ca2,sa2, ca3,sa3, ca4,sa4;
            float ca5,sa5, ca6,sa6, ca7,sa7, ca8,sa8, ca9,sa9;
            angNorm(q0.x,q0.y, ca0,sa0);  angNorm(q0.z,q0.w, ca1,sa1);
            angNorm(q1.x,q1.y, ca2,sa2);  angNorm(q1.z,q1.w, ca3,sa3);
            angNorm(q2.x,q2.y, ca4,sa4);  angNorm(q2.z,q2.w, ca5,sa5);
            angNorm(q3.x,q3.y, ca6,sa6);  angNorm(q3.z,q3.w, ca7,sa7);
            angNorm(q4.x,q4.y, ca8,sa8);  angNorm(q4.z,q4.w, ca9,sa9);

            // F1..F3
            float4 rw;
            rw = rowMat(f0r, rb +  0); rotXrow(rw, ca0, sa0);
            *reinterpret_cast<float4*>(fl + 1*FRS + i*4) = rw;
            *reinterpret_cast<float4*>(fg + 16 + i*4) = rw;
            rw = rowMat(f0r, rb + 16); rotXrow(rw, ca1, sa1);
            *reinterpret_cast<float4*>(fl + 2*FRS + i*4) = rw;
            *reinterpret_cast<float4*>(fg + 32 + i*4) = rw;
            rw = rowMat(f0r, rb + 32); rotXrow(rw, ca2, sa2);
            *reinterpret_cast<float4*>(fl + 3*FRS + i*4) = rw;
            *reinterpret_cast<float4*>(fg + 48 + i*4) = rw;

            // CB axes (redundant)
            const float* bxp = xibf + (size_t)s * 144;
            float4 b0 = reinterpret_cast<const float4*>(bxp)[0];
            float4 b1 = reinterpret_cast<const float4*>(bxp)[1];
            float4 b2 = reinterpret_cast<const float4*>(bxp)[2];
            float4 b4 = reinterpret_cast<const float4*>(bxp)[4];

            float NCr0 = 0.5f*(b2.x + b0.x), NCr1 = 0.5f*(b2.y + b0.y), NCr2 = 0.5f*(b2.z + b0.z);
            float ba0 = b4.x - b1.x, ba1 = b4.y - b1.y, ba2 = b4.z - b1.z;
            float w0 = NCr0 - b1.x, w1 = NCr1 - b1.y, w2 = NCr2 - b1.z;
            float x10 = ba1*w2 - ba2*w1, x11 = ba2*w0 - ba0*w2, x12 = ba0*w1 - ba1*w0;
            float in1 = rsqz(x10*x10 + x11*x11 + x12*x12);
            x10 *= in1; x11 *= in1; x12 *= in1;
            float NCp0 = b2.x - b0.x, NCp1 = b2.y - b0.y, NCp2 = b2.z - b0.z;
            float dp = NCp0*NCr0 + NCp1*NCr1 + NCp2*NCr2;
            float dr = NCr0*NCr0 + NCr1*NCr1 + NCr2*NCr2;
            float sf = dp / dr;
            float g0 = NCp0 - sf*NCr0, g1 = NCp1 - sf*NCr1, g2 = NCp2 - sf*NCr2;
            float x20 = ba1*g2 - ba2*g1, x21 = ba2*g0 - ba0*g2, x22 = ba0*g1 - ba1*g0;
            float in2 = rsqz(x20*x20 + x21*x21 + x22*x22);
            x20 *= in2; x21 *= in2; x22 *= in2;

            float G1[3][3], G2[3][3];
            rotAxis3(G1, ca7, sa7, x10, x11, x12);
            rotAxis3(G2, ca8, sa8, x20, x21, x22);

            // F8
            float4 f8r = applyG(applyG(f0r, G1), G2);
            *reinterpret_cast<float4*>(fl + 8*FRS + i*4) = f8r;
            *reinterpret_cast<float4*>(fg + 128 + i*4) = f8r;

            // F4..F7 suffix chain
            rw = rowMat(f8r, rb + 48); rotXrow(rw, ca3, sa3); rotZrow(rw, ca9, sa9);
            *reinterpret_cast<float4*>(fl + 4*FRS + i*4) = rw;
            *reinterpret_cast<float4*>(fg + 64 + i*4) = rw;
            rw = rowMat(rw, rb + 64); rotXrow(rw, ca4, sa4);
            *reinterpret_cast<float4*>(fl + 5*FRS + i*4) = rw;
            *reinterpret_cast<float4*>(fg + 80 + i*4) = rw;
            rw = rowMat(rw, rb + 80); rotXrow(rw, ca5, sa5);
            *reinterpret_cast<float4*>(fl + 6*FRS + i*4) = rw;
            *reinterpret_cast<float4*>(fg + 96 + i*4) = rw;
            rw = rowMat(rw, rb + 96); rotXrow(rw, ca6, sa6);
            *reinterpret_cast<float4*>(fl + 7*FRS + i*4) = rw;
            *reinterpret_cast<float4*>(fg + 112 + i*4) = rw;
        }
    } else {
        // ---------------- prefetch phase (waves 4-7) ----------------
#pragma unroll
        for (int k = 0; k < 5; ++k) {
            int c = tid + k*512;
            pf_idx[k] = 0;
            pf_v[k] = make_float4(0.f, 0.f, 0.f, 0.f);
            if (c < RPB*36) {
                int res = c / 36;
                int a = c - res*36;
                int tt = base + res;
                if (tt < BL) {
                    int ss = seq[tt];
                    pf_idx[k] = bidx[ss*36 + a];
                    pf_v[k]   = *reinterpret_cast<const float4*>(xibf + ((size_t)ss*36 + a)*4);
                }
            }
        }
    }
    __syncthreads();

    // ---------------- atom phase: all 8 waves, 2304 atoms ----------------
#pragma unroll
    for (int k = 0; k < 5; ++k) {
        int c = tid + k*512;
        if (c < RPB*36) {
            int res = c / 36;
            int a = c - res*36;
            int tt = base + res;
            if (tt < BL) {
                int idx; float4 v;
                if (wv >= 4) {
                    idx = pf_idx[k];
                    v   = pf_v[k];
                } else {
                    int ss = lds_seq[res];
                    idx = bidx[ss*36 + a];
                    v   = *reinterpret_cast<const float4*>(xibf + ((size_t)ss*36 + a)*4);
                }
                const float* fp = lds_fr + res*RSS + idx*FRS;
                float4 r0 = *reinterpret_cast<const float4*>(fp);
                float4 r1 = *reinterpret_cast<const float4*>(fp + 4);
                float4 r2 = *reinterpret_cast<const float4*>(fp + 8);
                size_t o = ((size_t)base*36 + c)*3;
                out_xyz[o+0] = r0.x*v.x + r0.y*v.y + r0.z*v.z + r0.w*v.w;
                out_xyz[o+1] = r1.x*v.x + r1.y*v.y + r1.z*v.z + r1.w*v.w;
                out_xyz[o+2] = r2.x*v.x + r2.y*v.y + r2.z*v.z + r2.w*v.w;
            }
        }
    }
}

// ---------------------------- launch ----------------------------

extern "C" void kernel_launch(void* const* d_in, const int* in_sizes, int n_in,
                              void* d_out, int out_size, void* d_ws, size_t ws_size,
                              hipStream_t stream) {
    const int*   seq    = (const int*)  d_in[0];
    const float* xyz    = (const float*)d_in[1];
    const float* alphas = (const float*)d_in[2];
    const int*   bidx   = (const int*)  d_in[3];
    const float* RTs    = (const float*)d_in[4];
    const float* xibf   = (const float*)d_in[5];
    float*       out    = (float*)d_out;

    int BL = in_sizes[0];                       // B * L
    float* out_xyz = out + (size_t)BL * 144;

    int blocks = (BL + RPB - 1) / RPB;
    fused_kernel<<<blocks, 512, 0, stream>>>(seq, xyz, alphas, bidx, RTs, xibf,
                                             out, out_xyz, BL);
}

// Round 12
// 15.019 us; speedup vs baseline: 1.5751x; 1.1616x over previous
//
#include <hip/hip_runtime.h>

#define RPB 64              // residues per block (4 lanes per residue, 16 residues per wave)
#define FRS 14              // LDS floats per frame: rows 0..2 only (12) + 2 pad, 8B-aligned
#define RSS (9*FRS)         // 126 floats per residue (504B) -> 31.5 KB/block -> 4 blocks/CU

// ---------- helpers ----------

__device__ __forceinline__ float rsqz(float d) { return rsqrtf(fmaxf(d, 1e-24f)); }

__device__ __forceinline__ void angNorm(float x, float y, float& c, float& s) {
    float inv = rsqz(x*x + y*y);
    c = x * inv; s = y * inv;
}

// row-vector times 4x4 matrix (matrix row-major, 4x float4)
__device__ __forceinline__ float4 rowMat(const float4 f, const float* __restrict__ B) {
    const float4* q = reinterpret_cast<const float4*>(B);
    float4 b0 = q[0], b1 = q[1], b2 = q[2], b3 = q[3];
    float4 o;
    o.x = f.x*b0.x + f.y*b1.x + f.z*b2.x + f.w*b3.x;
    o.y = f.x*b0.y + f.y*b1.y + f.z*b2.y + f.w*b3.y;
    o.z = f.x*b0.z + f.y*b1.z + f.z*b2.z + f.w*b3.z;
    o.w = f.x*b0.w + f.y*b1.w + f.z*b2.w + f.w*b3.w;
    return o;
}

__device__ __forceinline__ void rotXrow(float4& v, float c, float s) {
    float v1 = v.y, v2 = v.z;
    v.y = c*v1 + s*v2;
    v.z = c*v2 - s*v1;
}

__device__ __forceinline__ void rotZrow(float4& v, float c, float s) {
    float v0 = v.x, v1 = v.y;
    v.x = c*v0 + s*v1;
    v.y = c*v1 - s*v0;
}

__device__ __forceinline__ float4 applyG(const float4 f, const float G[3][3]) {
    float4 o;
    o.x = f.x*G[0][0] + f.y*G[1][0] + f.z*G[2][0];
    o.y = f.x*G[0][1] + f.y*G[1][1] + f.z*G[2][1];
    o.z = f.x*G[0][2] + f.y*G[1][2] + f.z*G[2][2];
    o.w = f.w;
    return o;
}

__device__ __forceinline__ void rotAxis3(float G[3][3], float c, float s,
                                         float u0, float u1, float u2) {
    float omc = 1.0f - c;
    G[0][0] = c + u0*u0*omc;    G[0][1] = u0*u1*omc - u2*s; G[0][2] = u0*u2*omc + u1*s;
    G[1][0] = u0*u1*omc + u2*s; G[1][1] = c + u1*u1*omc;    G[1][2] = u1*u2*omc - u0*s;
    G[2][0] = u0*u2*omc - u1*s; G[2][1] = u1*u2*omc + u0*s; G[2][2] = c + u2*u2*omc;
}

// write one frame row (i<3 only) to LDS as 2x float2 (8B aligned: FRS,RSS even)
__device__ __forceinline__ void ldsRow(float* fl, int frame, int i, const float4 v) {
    if (i < 3) {
        float* d = fl + frame*FRS + i*4;
        *reinterpret_cast<float2*>(d)     = make_float2(v.x, v.y);
        *reinterpret_cast<float2*>(d + 2) = make_float2(v.z, v.w);
    }
}

// ---------------------------- fused kernel ----------------------------
// 256 threads = 4 waves, fully independent (NO barriers). 4 lanes per
// residue; lane i carries row i of every frame through the recurrence
// F_next = F_prev @ M (row-decomposable). Identical code on all lanes.
// Frames: rows 0-2 -> LDS (atom gather, same-wave -> intra-wave lgkmcnt
// ordering suffices); all 4 rows -> global from registers.
// Atom phase: same wave, 576 atoms = 9*64.

__global__ __launch_bounds__(256, 4) void fused_kernel(
    const int*   __restrict__ seq,     // (BL)
    const float* __restrict__ xyz,     // (BL,3,3)
    const float* __restrict__ alphas,  // (BL,10,2)
    const int*   __restrict__ bidx,    // (NAA,36)
    const float* __restrict__ RTs,     // (NAA,7,4,4)
    const float* __restrict__ xibf,    // (NAA,36,4)
    float*       __restrict__ out_fr,  // (BL,9,4,4)
    float*       __restrict__ out_xyz, // (BL,36,3)
    int BL)
{
    __shared__ __align__(16) float lds_fr[RPB * RSS];   // 31.5 KB
    __shared__ int lds_seq[RPB];

    const int tid   = threadIdx.x;
    const int lane  = tid & 63;
    const int wv    = tid >> 6;
    const int i     = lane & 3;             // row index 0..3
    const int res   = wv*16 + (lane >> 2);  // residue within block
    const int base  = blockIdx.x * RPB;
    const int t     = base + res;
    const bool valid = (t < BL);

    float* fl = lds_fr + res * RSS;
    float* fg = out_fr + (size_t)t * 144;

    if (valid) {
        int s = seq[t];
        if (i == 0) lds_seq[res] = s;
        const float* rb = RTs + (size_t)s * 112;
        const float* al = alphas + (size_t)t * 20;

        // ---- Gram-Schmidt (redundant across the 4 lanes) ----
        const float* p = xyz + (size_t)t * 9;
        float N0=p[0], N1=p[1], N2=p[2];
        float A0=p[3], A1=p[4], A2=p[5];
        float C0=p[6], C1=p[7], C2=p[8];
        float v10=C0-A0, v11=C1-A1, v12=C2-A2;
        float v20=N0-A0, v21=N1-A1, v22=N2-A2;
        float i1 = rsqz(v10*v10 + v11*v11 + v12*v12);
        float e10=v10*i1, e11=v11*i1, e12=v12*i1;
        float d  = e10*v20 + e11*v21 + e12*v22;
        float u20=v20-e10*d, u21=v21-e11*d, u22=v22-e12*d;
        float i2 = rsqz(u20*u20 + u21*u21 + u22*u22);
        float e20=u20*i2, e21=u21*i2, e22=u22*i2;
        float e30=e11*e22 - e12*e21;
        float e31=e12*e20 - e10*e22;
        float e32=e10*e21 - e11*e20;

        bool c0 = (i==0), c1 = (i==1), c2 = (i==2);
        float4 f0r;
        f0r.x = c0?e10 : c1?e11 : c2?e12 : 0.f;
        f0r.y = c0?e20 : c1?e21 : c2?e22 : 0.f;
        f0r.z = c0?e30 : c1?e31 : c2?e32 : 0.f;
        f0r.w = c0?A0  : c1?A1  : c2?A2  : 1.f;
        ldsRow(fl, 0, i, f0r);
        *reinterpret_cast<float4*>(fg + i*4) = f0r;

        // ---- angles ----
        const float4* a4p = reinterpret_cast<const float4*>(al);
        float4 q0 = a4p[0], q1 = a4p[1], q2 = a4p[2], q3 = a4p[3], q4 = a4p[4];
        float ca0,sa0, ca1,sa1, ca2,sa2, ca3,sa3, ca4,sa4;
        float ca5,sa5, ca6,sa6, ca7,sa7, ca8,sa8, ca9,sa9;
        angNorm(q0.x,q0.y, ca0,sa0);  angNorm(q0.z,q0.w, ca1,sa1);
        angNorm(q1.x,q1.y, ca2,sa2);  angNorm(q1.z,q1.w, ca3,sa3);
        angNorm(q2.x,q2.y, ca4,sa4);  angNorm(q2.z,q2.w, ca5,sa5);
        angNorm(q3.x,q3.y, ca6,sa6);  angNorm(q3.z,q3.w, ca7,sa7);
        angNorm(q4.x,q4.y, ca8,sa8);  angNorm(q4.z,q4.w, ca9,sa9);

        // ---- F1..F3 ----
        float4 rw;
        rw = rowMat(f0r, rb +  0); rotXrow(rw, ca0, sa0);
        ldsRow(fl, 1, i, rw);
        *reinterpret_cast<float4*>(fg + 16 + i*4) = rw;
        rw = rowMat(f0r, rb + 16); rotXrow(rw, ca1, sa1);
        ldsRow(fl, 2, i, rw);
        *reinterpret_cast<float4*>(fg + 32 + i*4) = rw;
        rw = rowMat(f0r, rb + 32); rotXrow(rw, ca2, sa2);
        ldsRow(fl, 3, i, rw);
        *reinterpret_cast<float4*>(fg + 48 + i*4) = rw;

        // ---- CB axes (redundant) ----
        const float* bxp = xibf + (size_t)s * 144;
        float4 b0 = reinterpret_cast<const float4*>(bxp)[0];
        float4 b1 = reinterpret_cast<const float4*>(bxp)[1];
        float4 b2 = reinterpret_cast<const float4*>(bxp)[2];
        float4 b4 = reinterpret_cast<const float4*>(bxp)[4];

        float NCr0 = 0.5f*(b2.x + b0.x), NCr1 = 0.5f*(b2.y + b0.y), NCr2 = 0.5f*(b2.z + b0.z);
        float ba0 = b4.x - b1.x, ba1 = b4.y - b1.y, ba2 = b4.z - b1.z;
        float w0 = NCr0 - b1.x, w1 = NCr1 - b1.y, w2 = NCr2 - b1.z;
        float x10 = ba1*w2 - ba2*w1, x11 = ba2*w0 - ba0*w2, x12 = ba0*w1 - ba1*w0;
        float in1 = rsqz(x10*x10 + x11*x11 + x12*x12);
        x10 *= in1; x11 *= in1; x12 *= in1;
        float NCp0 = b2.x - b0.x, NCp1 = b2.y - b0.y, NCp2 = b2.z - b0.z;
        float dp = NCp0*NCr0 + NCp1*NCr1 + NCp2*NCr2;
        float dr = NCr0*NCr0 + NCr1*NCr1 + NCr2*NCr2;
        float sf = dp / dr;
        float g0 = NCp0 - sf*NCr0, g1 = NCp1 - sf*NCr1, g2 = NCp2 - sf*NCr2;
        float x20 = ba1*g2 - ba2*g1, x21 = ba2*g0 - ba0*g2, x22 = ba0*g1 - ba1*g0;
        float in2 = rsqz(x20*x20 + x21*x21 + x22*x22);
        x20 *= in2; x21 *= in2; x22 *= in2;

        float G1[3][3], G2[3][3];
        rotAxis3(G1, ca7, sa7, x10, x11, x12);
        rotAxis3(G2, ca8, sa8, x20, x21, x22);

        // ---- F8 ----
        float4 f8r = applyG(applyG(f0r, G1), G2);
        ldsRow(fl, 8, i, f8r);
        *reinterpret_cast<float4*>(fg + 128 + i*4) = f8r;

        // ---- F4..F7 suffix chain ----
        rw = rowMat(f8r, rb + 48); rotXrow(rw, ca3, sa3); rotZrow(rw, ca9, sa9);
        ldsRow(fl, 4, i, rw);
        *reinterpret_cast<float4*>(fg + 64 + i*4) = rw;
        rw = rowMat(rw, rb + 64); rotXrow(rw, ca4, sa4);
        ldsRow(fl, 5, i, rw);
        *reinterpret_cast<float4*>(fg + 80 + i*4) = rw;
        rw = rowMat(rw, rb + 80); rotXrow(rw, ca5, sa5);
        ldsRow(fl, 6, i, rw);
        *reinterpret_cast<float4*>(fg + 96 + i*4) = rw;
        rw = rowMat(rw, rb + 96); rotXrow(rw, ca6, sa6);
        ldsRow(fl, 7, i, rw);
        *reinterpret_cast<float4*>(fg + 112 + i*4) = rw;
    }

    // ---- atom phase: same wave (no barriers; intra-wave LDS ordering via lgkmcnt) ----
    const int wbase = wv * 16;
#pragma unroll
    for (int k = 0; k < 9; ++k) {
        int c = k*64 + lane;              // 0..575 within this wave
        int lres = c / 36;
        int a = c - lres*36;
        int res2 = wbase + lres;
        int tt = base + res2;
        if (tt < BL) {
            int ss  = lds_seq[res2];
            int idx = bidx[ss*36 + a];
            float4 v = *reinterpret_cast<const float4*>(xibf + ((size_t)ss*36 + a)*4);
            const float* fp = lds_fr + res2*RSS + idx*FRS;
            float2 r00 = *reinterpret_cast<const float2*>(fp + 0);
            float2 r01 = *reinterpret_cast<const float2*>(fp + 2);
            float2 r10 = *reinterpret_cast<const float2*>(fp + 4);
            float2 r11 = *reinterpret_cast<const float2*>(fp + 6);
            float2 r20 = *reinterpret_cast<const float2*>(fp + 8);
            float2 r21 = *reinterpret_cast<const float2*>(fp + 10);
            size_t o = ((size_t)(base + wbase)*36 + c)*3;   // dense in c per wave
            out_xyz[o+0] = r00.x*v.x + r00.y*v.y + r01.x*v.z + r01.y*v.w;
            out_xyz[o+1] = r10.x*v.x + r10.y*v.y + r11.x*v.z + r11.y*v.w;
            out_xyz[o+2] = r20.x*v.x + r20.y*v.y + r21.x*v.z + r21.y*v.w;
        }
    }
}

// ---------------------------- launch ----------------------------

extern "C" void kernel_launch(void* const* d_in, const int* in_sizes, int n_in,
                              void* d_out, int out_size, void* d_ws, size_t ws_size,
                              hipStream_t stream) {
    const int*   seq    = (const int*)  d_in[0];
    const float* xyz    = (const float*)d_in[1];
    const float* alphas = (const float*)d_in[2];
    const int*   bidx   = (const int*)  d_in[3];
    const float* RTs    = (const float*)d_in[4];
    const float* xibf   = (const float*)d_in[5];
    float*       out    = (float*)d_out;

    int BL = in_sizes[0];                       // B * L
    float* out_xyz = out + (size_t)BL * 144;

    int blocks = (BL + RPB - 1) / RPB;
    fused_kernel<<<blocks, 256, 0, stream>>>(seq, xyz, alphas, bidx, RTs, xibf,
                                             out, out_xyz, BL);
}

// Round 14
// 14.522 us; speedup vs baseline: 1.6290x; 1.0342x over previous
//
#include <hip/hip_runtime.h>

#define RPB 64              // residues per block (4 lanes per residue, 16 residues per wave)
#define FRS 14              // LDS floats per frame: rows 0..2 only (12) + 2 pad
#define RSS (9*FRS)         // 126 floats per residue frame store
#define RTS 116             // LDS floats per residue RT stage: 7*16 + 4 pad (16B-aligned rows)

// ---------- helpers ----------

__device__ __forceinline__ float rsqz(float d) { return rsqrtf(fmaxf(d, 1e-24f)); }

__device__ __forceinline__ void angNorm(float x, float y, float& c, float& s) {
    float inv = rsqz(x*x + y*y);
    c = x * inv; s = y * inv;
}

// row-vector times 4x4 matrix; B points at 16 floats (row-major), LDS or global
__device__ __forceinline__ float4 rowMat(const float4 f, const float* B) {
    float4 b0 = *reinterpret_cast<const float4*>(B);
    float4 b1 = *reinterpret_cast<const float4*>(B + 4);
    float4 b2 = *reinterpret_cast<const float4*>(B + 8);
    float4 b3 = *reinterpret_cast<const float4*>(B + 12);
    float4 o;
    o.x = f.x*b0.x + f.y*b1.x + f.z*b2.x + f.w*b3.x;
    o.y = f.x*b0.y + f.y*b1.y + f.z*b2.y + f.w*b3.y;
    o.z = f.x*b0.z + f.y*b1.z + f.z*b2.z + f.w*b3.z;
    o.w = f.x*b0.w + f.y*b1.w + f.z*b2.w + f.w*b3.w;
    return o;
}

__device__ __forceinline__ void rotXrow(float4& v, float c, float s) {
    float v1 = v.y, v2 = v.z;
    v.y = c*v1 + s*v2;
    v.z = c*v2 - s*v1;
}

__device__ __forceinline__ void rotZrow(float4& v, float c, float s) {
    float v0 = v.x, v1 = v.y;
    v.x = c*v0 + s*v1;
    v.y = c*v1 - s*v0;
}

__device__ __forceinline__ float4 applyG(const float4 f, const float G[3][3]) {
    float4 o;
    o.x = f.x*G[0][0] + f.y*G[1][0] + f.z*G[2][0];
    o.y = f.x*G[0][1] + f.y*G[1][1] + f.z*G[2][1];
    o.z = f.x*G[0][2] + f.y*G[1][2] + f.z*G[2][2];
    o.w = f.w;
    return o;
}

__device__ __forceinline__ void rotAxis3(float G[3][3], float c, float s,
                                         float u0, float u1, float u2) {
    float omc = 1.0f - c;
    G[0][0] = c + u0*u0*omc;    G[0][1] = u0*u1*omc - u2*s; G[0][2] = u0*u2*omc + u1*s;
    G[1][0] = u0*u1*omc + u2*s; G[1][1] = c + u1*u1*omc;    G[1][2] = u1*u2*omc - u0*s;
    G[2][0] = u0*u2*omc - u1*s; G[2][1] = u1*u2*omc + u0*s; G[2][2] = c + u2*u2*omc;
}

// write one frame row (i<3 only) to LDS as 2x float2 (8B aligned: FRS,RSS even)
__device__ __forceinline__ void ldsRow(float* fl, int frame, int i, const float4 v) {
    if (i < 3) {
        float* d = fl + frame*FRS + i*4;
        *reinterpret_cast<float2*>(d)     = make_float2(v.x, v.y);
        *reinterpret_cast<float2*>(d + 2) = make_float2(v.z, v.w);
    }
}

// ---------------------------- fused kernel ----------------------------
// 256 threads = 4 waves, fully independent (NO barriers). 4 lanes per
// residue; lane i carries row i of every frame (recurrence F_next = F_prev@M
// is row-decomposable). RT matrices are staged cooperatively through LDS:
// lane i loads ONLY row i of each of the 7 RT mats (7 coalesced float4
// loads; 4 lanes cover each 64B matrix), then rowMat reads full matrices
// from LDS (same-address broadcast within the group). Same-wave produce->
// consume everywhere: intra-wave lgkmcnt ordering suffices, no barriers.

__global__ __launch_bounds__(256, 2) void fused_kernel(
    const int*   __restrict__ seq,     // (BL)
    const float* __restrict__ xyz,     // (BL,3,3)
    const float* __restrict__ alphas,  // (BL,10,2)
    const int*   __restrict__ bidx,    // (NAA,36)
    const float* __restrict__ RTs,     // (NAA,7,4,4)
    const float* __restrict__ xibf,    // (NAA,36,4)
    float*       __restrict__ out_fr,  // (BL,9,4,4)
    float*       __restrict__ out_xyz, // (BL,36,3)
    int BL)
{
    __shared__ __align__(16) float lds_fr[RPB * RSS];   // 31.5 KB
    __shared__ __align__(16) float lds_rt[RPB * RTS];   // 29.0 KB
    __shared__ int lds_seq[RPB];

    const int tid   = threadIdx.x;
    const int lane  = tid & 63;
    const int wv    = tid >> 6;
    const int i     = lane & 3;             // row index 0..3
    const int res   = wv*16 + (lane >> 2);  // residue within block
    const int base  = blockIdx.x * RPB;
    const int t     = base + res;
    const bool valid = (t < BL);

    float* fl = lds_fr + res * RSS;
    float* rl = lds_rt + res * RTS;
    float* fg = out_fr + (size_t)t * 144;

    if (valid) {
        int s = seq[t];
        if (i == 0) lds_seq[res] = s;
        const float* rbase = RTs + (size_t)s * 112;
        const float* al = alphas + (size_t)t * 20;

        // ---- cooperative RT staging: lane i loads row i of each matrix ----
#pragma unroll
        for (int m = 0; m < 7; ++m) {
            float4 v = *reinterpret_cast<const float4*>(rbase + m*16 + i*4);
            *reinterpret_cast<float4*>(rl + m*16 + i*4) = v;
        }

        // ---- Gram-Schmidt (redundant across the 4 lanes) ----
        const float* p = xyz + (size_t)t * 9;
        float N0=p[0], N1=p[1], N2=p[2];
        float A0=p[3], A1=p[4], A2=p[5];
        float C0=p[6], C1=p[7], C2=p[8];
        float v10=C0-A0, v11=C1-A1, v12=C2-A2;
        float v20=N0-A0, v21=N1-A1, v22=N2-A2;
        float i1 = rsqz(v10*v10 + v11*v11 + v12*v12);
        float e10=v10*i1, e11=v11*i1, e12=v12*i1;
        float d  = e10*v20 + e11*v21 + e12*v22;
        float u20=v20-e10*d, u21=v21-e11*d, u22=v22-e12*d;
        float i2 = rsqz(u20*u20 + u21*u21 + u22*u22);
        float e20=u20*i2, e21=u21*i2, e22=u22*i2;
        float e30=e11*e22 - e12*e21;
        float e31=e12*e20 - e10*e22;
        float e32=e10*e21 - e11*e20;

        bool c0 = (i==0), c1 = (i==1), c2 = (i==2);
        float4 f0r;
        f0r.x = c0?e10 : c1?e11 : c2?e12 : 0.f;
        f0r.y = c0?e20 : c1?e21 : c2?e22 : 0.f;
        f0r.z = c0?e30 : c1?e31 : c2?e32 : 0.f;
        f0r.w = c0?A0  : c1?A1  : c2?A2  : 1.f;
        ldsRow(fl, 0, i, f0r);
        *reinterpret_cast<float4*>(fg + i*4) = f0r;

        // ---- angles ----
        const float4* a4p = reinterpret_cast<const float4*>(al);
        float4 q0 = a4p[0], q1 = a4p[1], q2 = a4p[2], q3 = a4p[3], q4 = a4p[4];
        float ca0,sa0, ca1,sa1, ca2,sa2, ca3,sa3, ca4,sa4;
        float ca5,sa5, ca6,sa6, ca7,sa7, ca8,sa8, ca9,sa9;
        angNorm(q0.x,q0.y, ca0,sa0);  angNorm(q0.z,q0.w, ca1,sa1);
        angNorm(q1.x,q1.y, ca2,sa2);  angNorm(q1.z,q1.w, ca3,sa3);
        angNorm(q2.x,q2.y, ca4,sa4);  angNorm(q2.z,q2.w, ca5,sa5);
        angNorm(q3.x,q3.y, ca6,sa6);  angNorm(q3.z,q3.w, ca7,sa7);
        angNorm(q4.x,q4.y, ca8,sa8);  angNorm(q4.z,q4.w, ca9,sa9);

        // ---- F1..F3 (RT mats from LDS) ----
        float4 rw;
        rw = rowMat(f0r, rl +  0); rotXrow(rw, ca0, sa0);
        ldsRow(fl, 1, i, rw);
        *reinterpret_cast<float4*>(fg + 16 + i*4) = rw;
        rw = rowMat(f0r, rl + 16); rotXrow(rw, ca1, sa1);
        ldsRow(fl, 2, i, rw);
        *reinterpret_cast<float4*>(fg + 32 + i*4) = rw;
        rw = rowMat(f0r, rl + 32); rotXrow(rw, ca2, sa2);
        ldsRow(fl, 3, i, rw);
        *reinterpret_cast<float4*>(fg + 48 + i*4) = rw;

        // ---- CB axes (redundant) ----
        const float* bxp = xibf + (size_t)s * 144;
        float4 b0 = reinterpret_cast<const float4*>(bxp)[0];
        float4 b1 = reinterpret_cast<const float4*>(bxp)[1];
        float4 b2 = reinterpret_cast<const float4*>(bxp)[2];
        float4 b4 = reinterpret_cast<const float4*>(bxp)[4];

        float NCr0 = 0.5f*(b2.x + b0.x), NCr1 = 0.5f*(b2.y + b0.y), NCr2 = 0.5f*(b2.z + b0.z);
        float ba0 = b4.x - b1.x, ba1 = b4.y - b1.y, ba2 = b4.z - b1.z;
        float w0 = NCr0 - b1.x, w1 = NCr1 - b1.y, w2 = NCr2 - b1.z;
        float x10 = ba1*w2 - ba2*w1, x11 = ba2*w0 - ba0*w2, x12 = ba0*w1 - ba1*w0;
        float in1 = rsqz(x10*x10 + x11*x11 + x12*x12);
        x10 *= in1; x11 *= in1; x12 *= in1;
        float NCp0 = b2.x - b0.x, NCp1 = b2.y - b0.y, NCp2 = b2.z - b0.z;
        float dp = NCp0*NCr0 + NCp1*NCr1 + NCp2*NCr2;
        float dr = NCr0*NCr0 + NCr1*NCr1 + NCr2*NCr2;
        float sf = dp / dr;
        float g0 = NCp0 - sf*NCr0, g1 = NCp1 - sf*NCr1, g2 = NCp2 - sf*NCr2;
        float x20 = ba1*g2 - ba2*g1, x21 = ba2*g0 - ba0*g2, x22 = ba0*g1 - ba1*g0;
        float in2 = rsqz(x20*x20 + x21*x21 + x22*x22);
        x20 *= in2; x21 *= in2; x22 *= in2;

        float G1[3][3], G2[3][3];
        rotAxis3(G1, ca7, sa7, x10, x11, x12);
        rotAxis3(G2, ca8, sa8, x20, x21, x22);

        // ---- F8 ----
        float4 f8r = applyG(applyG(f0r, G1), G2);
        ldsRow(fl, 8, i, f8r);
        *reinterpret_cast<float4*>(fg + 128 + i*4) = f8r;

        // ---- F4..F7 suffix chain (RT mats from LDS) ----
        rw = rowMat(f8r, rl + 48); rotXrow(rw, ca3, sa3); rotZrow(rw, ca9, sa9);
        ldsRow(fl, 4, i, rw);
        *reinterpret_cast<float4*>(fg + 64 + i*4) = rw;
        rw = rowMat(rw, rl + 64); rotXrow(rw, ca4, sa4);
        ldsRow(fl, 5, i, rw);
        *reinterpret_cast<float4*>(fg + 80 + i*4) = rw;
        rw = rowMat(rw, rl + 80); rotXrow(rw, ca5, sa5);
        ldsRow(fl, 6, i, rw);
        *reinterpret_cast<float4*>(fg + 96 + i*4) = rw;
        rw = rowMat(rw, rl + 96); rotXrow(rw, ca6, sa6);
        ldsRow(fl, 7, i, rw);
        *reinterpret_cast<float4*>(fg + 112 + i*4) = rw;
    }

    // ---- atom phase: same wave (no barriers; intra-wave LDS ordering via lgkmcnt) ----
    const int wbase = wv * 16;
#pragma unroll
    for (int k = 0; k < 9; ++k) {
        int c = k*64 + lane;              // 0..575 within this wave
        int lres = c / 36;
        int a = c - lres*36;
        int res2 = wbase + lres;
        int tt = base + res2;
        if (tt < BL) {
            int ss  = lds_seq[res2];
            int idx = bidx[ss*36 + a];
            float4 v = *reinterpret_cast<const float4*>(xibf + ((size_t)ss*36 + a)*4);
            const float* fp = lds_fr + res2*RSS + idx*FRS;
            float2 r00 = *reinterpret_cast<const float2*>(fp + 0);
            float2 r01 = *reinterpret_cast<const float2*>(fp + 2);
            float2 r10 = *reinterpret_cast<const float2*>(fp + 4);
            float2 r11 = *reinterpret_cast<const float2*>(fp + 6);
            float2 r20 = *reinterpret_cast<const float2*>(fp + 8);
            float2 r21 = *reinterpret_cast<const float2*>(fp + 10);
            size_t o = ((size_t)(base + wbase)*36 + c)*3;   // dense in c per wave
            out_xyz[o+0] = r00.x*v.x + r00.y*v.y + r01.x*v.z + r01.y*v.w;
            out_xyz[o+1] = r10.x*v.x + r10.y*v.y + r11.x*v.z + r11.y*v.w;
            out_xyz[o+2] = r20.x*v.x + r20.y*v.y + r21.x*v.z + r21.y*v.w;
        }
    }
}

// ---------------------------- launch ----------------------------

extern "C" void kernel_launch(void* const* d_in, const int* in_sizes, int n_in,
                              void* d_out, int out_size, void* d_ws, size_t ws_size,
                              hipStream_t stream) {
    const int*   seq    = (const int*)  d_in[0];
    const float* xyz    = (const float*)d_in[1];
    const float* alphas = (const float*)d_in[2];
    const int*   bidx   = (const int*)  d_in[3];
    const float* RTs    = (const float*)d_in[4];
    const float* xibf   = (const float*)d_in[5];
    float*       out    = (float*)d_out;

    int BL = in_sizes[0];                       // B * L
    float* out_xyz = out + (size_t)BL * 144;

    int blocks = (BL + RPB - 1) / RPB;
    fused_kernel<<<blocks, 256, 0, stream>>>(seq, xyz, alphas, bidx, RTs, xibf,
                                             out, out_xyz, BL);
}